// Round 1
// baseline (813.842 us; speedup 1.0000x reference)
//
#include <hip/hip_runtime.h>

// GIN layer: agg[b,dst] += x[b,src]; h = x + agg; out = relu(h@W1+b1)@W2 + b2
// B=2, N=50000, D=64, E=800000, EPS=0

#define N_NODES 50000
#define N_EDGES 800000
#define DIM 64
#define NROWS (2 * N_NODES)   // B*N = 100000 rows

// ---------------------------------------------------------------------------
// Kernel 1: scatter-add  agg[b, dst[e], :] += x[b, src[e], :]
// One thread handles (edge, 2 consecutive dims) for BOTH batches.
// 32 threads per edge -> uniform edge index within each half-wave,
// coalesced float2 gathers, 4 fp32 HW atomics per thread.
// ---------------------------------------------------------------------------
__global__ __launch_bounds__(256)
void gin_scatter(const float* __restrict__ x, const int* __restrict__ ei,
                 float* __restrict__ agg) {
    unsigned tid = blockIdx.x * 256u + threadIdx.x;
    unsigned e = tid >> 5;                 // 32 threads per edge
    if (e >= N_EDGES) return;
    unsigned d = (tid & 31u) * 2u;

    int s = ei[e];                         // src
    int t = ei[N_EDGES + e];               // dst

    // batch 0
    const float2 v0 = *reinterpret_cast<const float2*>(x + (size_t)s * DIM + d);
    float* a0 = agg + (size_t)t * DIM + d;
    unsafeAtomicAdd(a0,     v0.x);
    unsafeAtomicAdd(a0 + 1, v0.y);

    // batch 1
    const float2 v1 = *reinterpret_cast<const float2*>(x + (size_t)(N_NODES + s) * DIM + d);
    float* a1 = agg + (size_t)(N_NODES + t) * DIM + d;
    unsafeAtomicAdd(a1,     v1.x);
    unsafeAtomicAdd(a1 + 1, v1.y);
}

// ---------------------------------------------------------------------------
// Kernel 2: per-row fused MLP, in-place on the h buffer.
//   h = buf[row]; h1 = relu(h@W1+b1); buf[row] = h1@W2 + b2
// Weights staged in LDS once per block. 4 waves/block, 8 rows/wave.
// Row value broadcast via __shfl with compile-time lane (v_readlane).
// ---------------------------------------------------------------------------
#define MLP_ROWS 8

__global__ __launch_bounds__(256)
void gin_mlp(float* __restrict__ buf,
             const float* __restrict__ W1, const float* __restrict__ b1,
             const float* __restrict__ W2, const float* __restrict__ b2) {
    __shared__ float w1s[DIM * DIM];
    __shared__ float w2s[DIM * DIM];
    __shared__ float b1s[DIM];
    __shared__ float b2s[DIM];

    const int t = threadIdx.x;
    // 4096 floats each = 1024 float4; 256 threads -> 4 float4 per thread per mat
    for (int i = t; i < 1024; i += 256) {
        reinterpret_cast<float4*>(w1s)[i] = reinterpret_cast<const float4*>(W1)[i];
        reinterpret_cast<float4*>(w2s)[i] = reinterpret_cast<const float4*>(W2)[i];
    }
    if (t < DIM) { b1s[t] = b1[t]; b2s[t] = b2[t]; }
    __syncthreads();

    const int lane = t & 63;
    const int wave = t >> 6;
    const size_t row0 = ((size_t)blockIdx.x * 4 + wave) * MLP_ROWS;

    float xr[MLP_ROWS], h[MLP_ROWS], o[MLP_ROWS];

    #pragma unroll
    for (int j = 0; j < MLP_ROWS; ++j)
        xr[j] = buf[(row0 + j) * DIM + lane];

    #pragma unroll
    for (int j = 0; j < MLP_ROWS; ++j) h[j] = b1s[lane];

    #pragma unroll
    for (int k = 0; k < DIM; ++k) {
        float w = w1s[k * DIM + lane];
        #pragma unroll
        for (int j = 0; j < MLP_ROWS; ++j)
            h[j] = fmaf(__shfl(xr[j], k, 64), w, h[j]);
    }

    #pragma unroll
    for (int j = 0; j < MLP_ROWS; ++j) h[j] = fmaxf(h[j], 0.0f);

    #pragma unroll
    for (int j = 0; j < MLP_ROWS; ++j) o[j] = b2s[lane];

    #pragma unroll
    for (int k = 0; k < DIM; ++k) {
        float w = w2s[k * DIM + lane];
        #pragma unroll
        for (int j = 0; j < MLP_ROWS; ++j)
            o[j] = fmaf(__shfl(h[j], k, 64), w, o[j]);
    }

    #pragma unroll
    for (int j = 0; j < MLP_ROWS; ++j)
        buf[(row0 + j) * DIM + lane] = o[j];
}

// ---------------------------------------------------------------------------
extern "C" void kernel_launch(void* const* d_in, const int* in_sizes, int n_in,
                              void* d_out, int out_size, void* d_ws, size_t ws_size,
                              hipStream_t stream) {
    const float* x  = (const float*)d_in[0];
    const int*   ei = (const int*)d_in[1];
    const float* W1 = (const float*)d_in[2];
    const float* b1 = (const float*)d_in[3];
    const float* W2 = (const float*)d_in[4];
    const float* b2 = (const float*)d_in[5];
    float* out = (float*)d_out;

    // out <- x  (agg accumulator seeded with (1+eps)*x, eps=0)
    hipMemcpyAsync(out, x, sizeof(float) * (size_t)NROWS * DIM,
                   hipMemcpyDeviceToDevice, stream);

    // scatter-add: E edges * 32 threads = 25.6M threads
    gin_scatter<<<(N_EDGES * 32 + 255) / 256, 256, 0, stream>>>(x, ei, out);

    // fused MLP in-place: 100000 rows / (4 waves * 8 rows) = 3125 blocks
    gin_mlp<<<NROWS / (4 * MLP_ROWS), 256, 0, stream>>>(out, W1, b1, W2, b2);
}

// Round 2
// 304.003 us; speedup vs baseline: 2.6771x; 2.6771x over previous
//
#include <hip/hip_runtime.h>

// GIN layer: agg[b,dst] += x[b,src]; h = x + agg; out = relu(h@W1+b1)@W2 + b2
// B=2, N=50000, D=64, E=800000, EPS=0
//
// R2 strategy: replace 102.4M fp32 atomics (atomic-throughput bound, 652us)
// with CSR build (hist + scan + fill, int atomics on L2-resident counters)
// followed by a fused gather+MLP kernel (coalesced 256B row reads from L2/L3).

#define N_NODES 50000
#define N_EDGES 800000
#define DIM 64
#define NROWS (2 * N_NODES)
#define SCAN_BLOCKS 196          // ceil(50000/256)

// ws layout (bytes):
//   [0,      1024)     blockSums  u32[256]
//   [1024,   201024)   counts     u32[50000]   (memset 0 each call)
//   [201024, 401024)   start      u32[50000]
//   [401024, 3601024)  adj        u32[800000]
#define WS_NEEDED 3601024u

// ---------------------------------------------------------------------------
// CSR build
// ---------------------------------------------------------------------------
__global__ __launch_bounds__(256)
void k_hist(const int* __restrict__ ei, unsigned* __restrict__ counts) {
    int e = blockIdx.x * 256 + threadIdx.x;
    if (e < N_EDGES) atomicAdd(&counts[ei[N_EDGES + e]], 1u);
}

__global__ __launch_bounds__(256)
void k_scan1(const unsigned* __restrict__ counts, unsigned* __restrict__ blockSums) {
    __shared__ unsigned ls[4];
    int i = blockIdx.x * 256 + threadIdx.x;
    unsigned v = (i < N_NODES) ? counts[i] : 0u;
    #pragma unroll
    for (int off = 32; off; off >>= 1) v += __shfl_down(v, off, 64);
    if ((threadIdx.x & 63) == 0) ls[threadIdx.x >> 6] = v;
    __syncthreads();
    if (threadIdx.x == 0) blockSums[blockIdx.x] = ls[0] + ls[1] + ls[2] + ls[3];
}

__global__ __launch_bounds__(256)
void k_scan2(unsigned* __restrict__ blockSums) {
    __shared__ unsigned s[256];
    int t = threadIdx.x;
    unsigned v = (t < SCAN_BLOCKS) ? blockSums[t] : 0u;
    s[t] = v;
    __syncthreads();
    for (int off = 1; off < 256; off <<= 1) {
        unsigned val = (t >= off) ? s[t - off] : 0u;
        __syncthreads();
        s[t] += val;
        __syncthreads();
    }
    if (t < SCAN_BLOCKS) blockSums[t] = s[t] - v;   // exclusive prefix of block sums
}

__global__ __launch_bounds__(256)
void k_scan3(const unsigned* __restrict__ counts, const unsigned* __restrict__ blockSums,
             unsigned* __restrict__ start) {
    __shared__ unsigned s[256];
    int t = threadIdx.x;
    int i = blockIdx.x * 256 + t;
    unsigned v = (i < N_NODES) ? counts[i] : 0u;
    s[t] = v;
    __syncthreads();
    for (int off = 1; off < 256; off <<= 1) {
        unsigned val = (t >= off) ? s[t - off] : 0u;
        __syncthreads();
        s[t] += val;
        __syncthreads();
    }
    if (i < N_NODES) start[i] = s[t] - v + blockSums[blockIdx.x];  // global exclusive
}

__global__ __launch_bounds__(256)
void k_fill(const int* __restrict__ ei, unsigned* __restrict__ start,
            unsigned* __restrict__ adj) {
    int e = blockIdx.x * 256 + threadIdx.x;
    if (e >= N_EDGES) return;
    int s = ei[e];
    int d = ei[N_EDGES + e];
    unsigned pos = atomicAdd(&start[d], 1u);   // start becomes inclusive prefix (=end)
    adj[pos] = (unsigned)s;
}

// ---------------------------------------------------------------------------
// Fused gather + MLP. One wave per 4 nodes (both batches), lane = dim.
// endOff[d] = end index of bucket d (inclusive prefix after fill).
// ---------------------------------------------------------------------------
#define NODES_PER_WAVE 4

__global__ __launch_bounds__(256)
void k_gather_mlp(const float* __restrict__ x,
                  const unsigned* __restrict__ endOff,
                  const unsigned* __restrict__ adj,
                  const float* __restrict__ W1, const float* __restrict__ b1,
                  const float* __restrict__ W2, const float* __restrict__ b2,
                  float* __restrict__ out) {
    __shared__ float w1s[DIM * DIM];
    __shared__ float w2s[DIM * DIM];
    __shared__ float b1s[DIM], b2s[DIM];

    const int t = threadIdx.x;
    for (int i = t; i < 1024; i += 256) {
        reinterpret_cast<float4*>(w1s)[i] = reinterpret_cast<const float4*>(W1)[i];
        reinterpret_cast<float4*>(w2s)[i] = reinterpret_cast<const float4*>(W2)[i];
    }
    if (t < DIM) { b1s[t] = b1[t]; b2s[t] = b2[t]; }
    __syncthreads();

    const int lane = t & 63;
    const int wave = t >> 6;
    const int node0 = (blockIdx.x * 4 + wave) * NODES_PER_WAVE;

    float r[2 * NODES_PER_WAVE];   // batch0 rows [0..3], batch1 rows [4..7]

    for (int j = 0; j < NODES_PER_WAVE; ++j) {
        const int d = node0 + j;
        unsigned beg = (d == 0) ? 0u : endOff[d - 1];
        const unsigned end = endOff[d];
        float a0 = x[(size_t)d * DIM + lane];               // (1+eps)*x, eps=0
        float a1 = x[(size_t)(N_NODES + d) * DIM + lane];
        while (beg < end) {
            unsigned chunk = end - beg;
            if (chunk > 64u) chunk = 64u;
            unsigned sv = 0u;
            if ((unsigned)lane < chunk) sv = adj[beg + lane];
            #pragma unroll 4
            for (unsigned k = 0; k < chunk; ++k) {
                unsigned s = (unsigned)__shfl((int)sv, (int)k, 64);
                a0 += x[(size_t)s * DIM + lane];
                a1 += x[(size_t)(N_NODES + s) * DIM + lane];
            }
            beg += chunk;
        }
        r[j] = a0;
        r[NODES_PER_WAVE + j] = a1;
    }

    // MLP on the wave's 8 rows; weights broadcast from LDS, rows via v_readlane.
    float h[8], o[8];
    #pragma unroll
    for (int j = 0; j < 8; ++j) h[j] = b1s[lane];
    #pragma unroll
    for (int k = 0; k < DIM; ++k) {
        float w = w1s[k * DIM + lane];
        #pragma unroll
        for (int j = 0; j < 8; ++j) h[j] = fmaf(__shfl(r[j], k, 64), w, h[j]);
    }
    #pragma unroll
    for (int j = 0; j < 8; ++j) h[j] = fmaxf(h[j], 0.0f);
    #pragma unroll
    for (int j = 0; j < 8; ++j) o[j] = b2s[lane];
    #pragma unroll
    for (int k = 0; k < DIM; ++k) {
        float w = w2s[k * DIM + lane];
        #pragma unroll
        for (int j = 0; j < 8; ++j) o[j] = fmaf(__shfl(h[j], k, 64), w, o[j]);
    }

    #pragma unroll
    for (int j = 0; j < NODES_PER_WAVE; ++j) {
        const int d = node0 + j;
        out[(size_t)d * DIM + lane] = o[j];
        out[(size_t)(N_NODES + d) * DIM + lane] = o[NODES_PER_WAVE + j];
    }
}

// ---------------------------------------------------------------------------
// Fallback path (R1) in case ws_size is too small for the CSR.
// ---------------------------------------------------------------------------
__global__ __launch_bounds__(256)
void gin_scatter(const float* __restrict__ x, const int* __restrict__ ei,
                 float* __restrict__ agg) {
    unsigned tid = blockIdx.x * 256u + threadIdx.x;
    unsigned e = tid >> 5;
    if (e >= N_EDGES) return;
    unsigned d = (tid & 31u) * 2u;
    int s = ei[e];
    int dst = ei[N_EDGES + e];
    const float2 v0 = *reinterpret_cast<const float2*>(x + (size_t)s * DIM + d);
    float* a0 = agg + (size_t)dst * DIM + d;
    unsafeAtomicAdd(a0, v0.x);
    unsafeAtomicAdd(a0 + 1, v0.y);
    const float2 v1 = *reinterpret_cast<const float2*>(x + (size_t)(N_NODES + s) * DIM + d);
    float* a1 = agg + (size_t)(N_NODES + dst) * DIM + d;
    unsafeAtomicAdd(a1, v1.x);
    unsafeAtomicAdd(a1 + 1, v1.y);
}

__global__ __launch_bounds__(256)
void gin_mlp(float* __restrict__ buf,
             const float* __restrict__ W1, const float* __restrict__ b1,
             const float* __restrict__ W2, const float* __restrict__ b2) {
    __shared__ float w1s[DIM * DIM];
    __shared__ float w2s[DIM * DIM];
    __shared__ float b1s[DIM], b2s[DIM];
    const int t = threadIdx.x;
    for (int i = t; i < 1024; i += 256) {
        reinterpret_cast<float4*>(w1s)[i] = reinterpret_cast<const float4*>(W1)[i];
        reinterpret_cast<float4*>(w2s)[i] = reinterpret_cast<const float4*>(W2)[i];
    }
    if (t < DIM) { b1s[t] = b1[t]; b2s[t] = b2[t]; }
    __syncthreads();
    const int lane = t & 63;
    const int wave = t >> 6;
    const size_t row0 = ((size_t)blockIdx.x * 4 + wave) * 8;
    float xr[8], h[8], o[8];
    #pragma unroll
    for (int j = 0; j < 8; ++j) xr[j] = buf[(row0 + j) * DIM + lane];
    #pragma unroll
    for (int j = 0; j < 8; ++j) h[j] = b1s[lane];
    #pragma unroll
    for (int k = 0; k < DIM; ++k) {
        float w = w1s[k * DIM + lane];
        #pragma unroll
        for (int j = 0; j < 8; ++j) h[j] = fmaf(__shfl(xr[j], k, 64), w, h[j]);
    }
    #pragma unroll
    for (int j = 0; j < 8; ++j) h[j] = fmaxf(h[j], 0.0f);
    #pragma unroll
    for (int j = 0; j < 8; ++j) o[j] = b2s[lane];
    #pragma unroll
    for (int k = 0; k < DIM; ++k) {
        float w = w2s[k * DIM + lane];
        #pragma unroll
        for (int j = 0; j < 8; ++j) o[j] = fmaf(__shfl(h[j], k, 64), w, o[j]);
    }
    #pragma unroll
    for (int j = 0; j < 8; ++j) buf[(row0 + j) * DIM + lane] = o[j];
}

// ---------------------------------------------------------------------------
extern "C" void kernel_launch(void* const* d_in, const int* in_sizes, int n_in,
                              void* d_out, int out_size, void* d_ws, size_t ws_size,
                              hipStream_t stream) {
    const float* x  = (const float*)d_in[0];
    const int*   ei = (const int*)d_in[1];
    const float* W1 = (const float*)d_in[2];
    const float* b1 = (const float*)d_in[3];
    const float* W2 = (const float*)d_in[4];
    const float* b2 = (const float*)d_in[5];
    float* out = (float*)d_out;

    if (ws_size >= WS_NEEDED) {
        unsigned* blockSums = (unsigned*)d_ws;
        unsigned* counts = (unsigned*)((char*)d_ws + 1024);
        unsigned* start  = (unsigned*)((char*)d_ws + 201024);
        unsigned* adj    = (unsigned*)((char*)d_ws + 401024);

        hipMemsetAsync(counts, 0, N_NODES * sizeof(unsigned), stream);
        k_hist <<<(N_EDGES + 255) / 256, 256, 0, stream>>>(ei, counts);
        k_scan1<<<SCAN_BLOCKS, 256, 0, stream>>>(counts, blockSums);
        k_scan2<<<1, 256, 0, stream>>>(blockSums);
        k_scan3<<<SCAN_BLOCKS, 256, 0, stream>>>(counts, blockSums, start);
        k_fill <<<(N_EDGES + 255) / 256, 256, 0, stream>>>(ei, start, adj);
        // 50000 nodes / (4 waves * 4 nodes) = 3125 blocks
        k_gather_mlp<<<N_NODES / (4 * NODES_PER_WAVE), 256, 0, stream>>>(
            x, start, adj, W1, b1, W2, b2, out);
    } else {
        hipMemcpyAsync(out, x, sizeof(float) * (size_t)NROWS * DIM,
                       hipMemcpyDeviceToDevice, stream);
        gin_scatter<<<(N_EDGES * 32 + 255) / 256, 256, 0, stream>>>(x, ei, out);
        gin_mlp<<<NROWS / 32, 256, 0, stream>>>(out, W1, b1, W2, b2);
    }
}